// Round 5
// baseline (471.813 us; speedup 1.0000x reference)
//
#include <hip/hip_runtime.h>
#include <hip/hip_bf16.h>

// LocalBlock: fused tpose+LN1 -> qkv GEMM -> multi-dilate local attn(+xn) -> proj GEMM(+x)
//            -> LN2 -> fc1+gelu -> fc2(+x, transposed out)
// A-resident barrier-free GEMMs: A[32][K-chunk] staged once in LDS, B from bricked weights.

#define B_   8
#define C_   384
#define W_   56
#define HW_  3136
#define N_   25088
#define HD_  32
#define HID_ 1536
#define C3_  1152

typedef __attribute__((ext_vector_type(8))) short short8v;
typedef __attribute__((ext_vector_type(4))) float f32x4;
typedef __attribute__((ext_vector_type(4))) unsigned short ushort4v;

__device__ __forceinline__ float bf2f(unsigned short u) {
  union { float f; unsigned u; } c; c.u = ((unsigned)u) << 16; return c.f;
}
__device__ __forceinline__ unsigned short f2bf(float f) {
  unsigned u = __float_as_uint(f);
  u = (u + 0x7FFFu + ((u >> 16) & 1u)) >> 16;
  return (unsigned short)u;
}

#define GLL(gsrc, ldst) __builtin_amdgcn_global_load_lds( \
    (const __attribute__((address_space(1))) void*)(gsrc), \
    (__attribute__((address_space(3))) void*)(ldst), 16, 0, 0)

// ---------------- weight fp32 -> bf16 MFMA bricks ----------------
// brick: 16 n x 32 k = 512 ushort; lane = (n&15) + (((k>>3)&3)<<4), elem = k&7
// addr = ((n>>4)*(K>>5) + (k>>5))*512 + lane*8 + elem
__device__ __forceinline__ void brick_one(const float* src, unsigned short* dst,
                                          int idx, int K) {
  const int n = idx / K, k = idx - n * K;
  const int lane = (n & 15) + (((k >> 3) & 3) << 4);
  dst[(size_t)((n >> 4) * (K >> 5) + (k >> 5)) * 512 + lane * 8 + (k & 7)] = f2bf(src[idx]);
}
__global__ void repack_w(const float* __restrict__ qw, const float* __restrict__ pw,
                         const float* __restrict__ f1, const float* __restrict__ f2,
                         unsigned short* __restrict__ o) {
  int i = blockIdx.x * 256 + threadIdx.x;
  if (i < 442368)        brick_one(qw, o, i, 384);
  else if (i < 589824)   brick_one(pw, o + 442368, i - 442368, 384);
  else if (i < 1179648)  brick_one(f1, o + 589824, i - 589824, 384);
  else if (i < 1769472)  brick_one(f2, o + 1179648, i - 1179648, 1536);
}

// ---------------- fused transpose + LN1 ----------------
__global__ __launch_bounds__(256)
void tpose_ln(const float* __restrict__ x, float* __restrict__ xp,
              unsigned short* __restrict__ xnb,
              const float* __restrict__ gam, const float* __restrict__ bet) {
  __shared__ float ft[64][385];
  __shared__ float mstat[64], rstat[64];
  const int tid = threadIdx.x;
  const int nb0 = blockIdx.x * 64;
  const int bb = nb0 / HW_, hw0 = nb0 - bb * HW_;
  const float* xb = x + (size_t)bb * C_ * HW_ + hw0;
#pragma unroll
  for (int p = 0; p < 24; ++p) {
    const int c = p * 16 + (tid >> 4);
    f32x4 v = *(const f32x4*)&xb[(size_t)c * HW_ + (tid & 15) * 4];
#pragma unroll
    for (int j = 0; j < 4; ++j) ft[(tid & 15) * 4 + j][c] = v[j];
  }
  __syncthreads();
  const int l16 = tid & 15, g16 = tid >> 4;
#pragma unroll
  for (int rr = 0; rr < 4; ++rr) {
    const int row = g16 * 4 + rr;
    float s = 0.f, ss = 0.f;
#pragma unroll
    for (int k2 = 0; k2 < 24; ++k2) { float v = ft[row][l16 + k2 * 16]; s += v; ss += v * v; }
    s += __shfl_xor(s, 8); ss += __shfl_xor(ss, 8);
    s += __shfl_xor(s, 4); ss += __shfl_xor(ss, 4);
    s += __shfl_xor(s, 2); ss += __shfl_xor(ss, 2);
    s += __shfl_xor(s, 1); ss += __shfl_xor(ss, 1);
    if (l16 == 0) {
      const float mean = s * (1.f / 384.f);
      const float var = ss * (1.f / 384.f) - mean * mean;
      mstat[row] = mean; rstat[row] = rsqrtf(var + 1e-5f);
    }
  }
  __syncthreads();
  const int row = tid >> 2, part = tid & 3;
  const float mean = mstat[row], rstd = rstat[row];
  float* xpr = xp + (size_t)(nb0 + row) * C_ + part * 96;
  unsigned short* xr = xnb + (size_t)(nb0 + row) * C_ + part * 96;
#pragma unroll
  for (int q = 0; q < 12; ++q) {
    short8v o;
    f32x4 v0, v1;
#pragma unroll
    for (int e = 0; e < 8; ++e) {
      const int c = part * 96 + q * 8 + e;
      const float v = ft[row][c];
      if (e < 4) v0[e] = v; else v1[e - 4] = v;
      o[e] = (short)f2bf((v - mean) * rstd * gam[c] + bet[c]);
    }
    *(f32x4*)&xpr[q * 8] = v0;
    *(f32x4*)&xpr[q * 8 + 4] = v1;
    *(short8v*)&xr[q * 8] = o;
  }
}

// ---------------- row LayerNorm (fp32 in) -> bf16 out (LN2) ----------------
__global__ __launch_bounds__(256)
void ln_rows(const float* __restrict__ in, unsigned short* __restrict__ outb,
             const float* __restrict__ g, const float* __restrict__ bb) {
  const int row = blockIdx.x * 4 + (threadIdx.x >> 6);
  const int lane = threadIdx.x & 63;
  const float* rp = in + (size_t)row * C_;
  float v[6]; float s = 0.f, ss = 0.f;
#pragma unroll
  for (int j = 0; j < 6; ++j) { v[j] = rp[lane + j * 64]; s += v[j]; ss += v[j] * v[j]; }
#pragma unroll
  for (int off = 32; off; off >>= 1) { s += __shfl_xor(s, off); ss += __shfl_xor(ss, off); }
  const float mean = s * (1.f / 384.f);
  const float var = ss * (1.f / 384.f) - mean * mean;
  const float rstd = rsqrtf(var + 1e-5f);
  unsigned short* op = outb + (size_t)row * C_;
#pragma unroll
  for (int j = 0; j < 6; ++j) {
    const int c = lane + j * 64;
    op[c] = f2bf((v[j] - mean) * rstd * g[c] + bb[c]);
  }
}

// ---------------- A-resident barrier-free GEMM ----------------
// out[M,NOUT] = A[M,K] @ W[NOUT,K]^T.  Block = 32 rows, 4 waves, 24KB LDS.
// A chunk [32][384] staged once (XOR-swizzled via pre-swizzled source), one barrier,
// then waves independently sweep n-groups of NW cols; B fragments from bricks (L2).
// MODE 0: bf16 out (qkv), swapped mfma     MODE 1: f32 out = resid+v+bias (proj)
// MODE 2: bf16 gelu(v+bias) (fc1), swapped MODE 3: f32 d_out[B,C,HW] = resid+v+bias (fc2)
template <int MODE, int NOUT, int K, int NW>
__global__ __launch_bounds__(256, 3)
void gemmA(const unsigned short* __restrict__ A, const unsigned short* __restrict__ Wb,
           const float* __restrict__ bias, const float* __restrict__ resid,
           void* __restrict__ outp) {
  constexpr int NG = NOUT / NW, NFR = NW / 16, KCH = K / 384, KB = K >> 5;
  constexpr bool SWAP = (MODE == 0 || MODE == 2);
  __shared__ unsigned short smA[32 * 384];   // 24 KiB
  const int tid = threadIdx.x, l = tid & 63, wv = tid >> 6;
  const int fr = l & 15, gh = l >> 4;
  const int m0 = blockIdx.x * 32;

  auto stage = [&](int ck) {
#pragma unroll
    for (int r = 0; r < 6; ++r) {
      const int slot = tid + 256 * r;
      const int row = slot / 48, s = slot - row * 48;
      const unsigned short* src =
          A + (size_t)(m0 + row) * K + ck * 384 + (size_t)((s ^ (row & 7)) << 3);
      GLL(src, &smA[slot * 8]);
    }
  };

  auto ldA = [&](int mt, int kt) -> short8v {
    const int row = mt * 16 + fr;
    return *(const short8v*)&smA[row * 384 + ((((kt << 2) + gh) ^ (fr & 7)) << 3)];
  };

  auto kloop = [&](int g, int ck, f32x4 (&acc)[2][NFR]) {
    const unsigned short* bp = Wb + ((size_t)(g * NFR) * KB + ck * 12) * 512 + l * 8;
    short8v a0[2], a1[2], b0[NFR], b1[NFR];
#pragma unroll
    for (int mt = 0; mt < 2; ++mt) a0[mt] = ldA(mt, 0);
#pragma unroll
    for (int nt = 0; nt < NFR; ++nt) b0[nt] = *(const short8v*)(bp + (size_t)(nt * KB) * 512);
#pragma unroll
    for (int kt = 0; kt < 12; kt += 2) {
#pragma unroll
      for (int mt = 0; mt < 2; ++mt) a1[mt] = ldA(mt, kt + 1);
#pragma unroll
      for (int nt = 0; nt < NFR; ++nt)
        b1[nt] = *(const short8v*)(bp + (size_t)(nt * KB + kt + 1) * 512);
#pragma unroll
      for (int mt = 0; mt < 2; ++mt)
#pragma unroll
        for (int nt = 0; nt < NFR; ++nt) {
          if (SWAP)
            acc[mt][nt] = __builtin_amdgcn_mfma_f32_16x16x32_bf16(b0[nt], a0[mt], acc[mt][nt], 0, 0, 0);
          else
            acc[mt][nt] = __builtin_amdgcn_mfma_f32_16x16x32_bf16(a0[mt], b0[nt], acc[mt][nt], 0, 0, 0);
        }
      if (kt + 2 < 12) {
#pragma unroll
        for (int mt = 0; mt < 2; ++mt) a0[mt] = ldA(mt, kt + 2);
#pragma unroll
        for (int nt = 0; nt < NFR; ++nt)
          b0[nt] = *(const short8v*)(bp + (size_t)(nt * KB + kt + 2) * 512);
      }
#pragma unroll
      for (int mt = 0; mt < 2; ++mt)
#pragma unroll
        for (int nt = 0; nt < NFR; ++nt) {
          if (SWAP)
            acc[mt][nt] = __builtin_amdgcn_mfma_f32_16x16x32_bf16(b1[nt], a1[mt], acc[mt][nt], 0, 0, 0);
          else
            acc[mt][nt] = __builtin_amdgcn_mfma_f32_16x16x32_bf16(a1[mt], b1[nt], acc[mt][nt], 0, 0, 0);
        }
    }
  };

  if constexpr (KCH == 1) {
    stage(0);
    __syncthreads();
    for (int g = wv; g < NG; g += 4) {
      f32x4 acc[2][NFR] = {};
      kloop(g, 0, acc);
      if constexpr (MODE == 1) {
        float* out = (float*)outp;
#pragma unroll
        for (int mt = 0; mt < 2; ++mt)
#pragma unroll
          for (int nt = 0; nt < NFR; ++nt) {
            const int n = g * NW + nt * 16 + fr;
            const float bo = bias[n];
#pragma unroll
            for (int j = 0; j < 4; ++j) {
              const size_t ix = (size_t)(m0 + mt * 16 + (gh << 2) + j) * C_ + n;
              out[ix] = resid[ix] + acc[mt][nt][j] + bo;
            }
          }
      } else {
        // SWAP: m = mt*16+fr, n = g*NW + nt*16 + gh*4 + j
        unsigned short* op = (unsigned short*)outp;
#pragma unroll
        for (int mt = 0; mt < 2; ++mt) {
          const int m = m0 + mt * 16 + fr;
#pragma unroll
          for (int nt = 0; nt < NFR; ++nt) {
            const int n = g * NW + nt * 16 + (gh << 2);
            f32x4 v = acc[mt][nt];
            ushort4v pk;
            if constexpr (MODE == 2) {
              const f32x4 b4 = *(const f32x4*)&bias[n];
#pragma unroll
              for (int j = 0; j < 4; ++j) {
                const float xv = v[j] + b4[j];
                pk[j] = f2bf(0.5f * xv * (1.f + erff(xv * 0.70710678118f)));
              }
            } else {
#pragma unroll
              for (int j = 0; j < 4; ++j) pk[j] = f2bf(v[j]);
            }
            *(ushort4v*)&op[(size_t)m * NOUT + n] = pk;
          }
        }
      }
    }
  } else {
    // MODE 3 (fc2): K = 1536 in 4 chunks; acc persists across chunks for 2 passes.
    f32x4 acc2[2][2][NFR] = {};
    for (int ck = 0; ck < KCH; ++ck) {
      if (ck) __syncthreads();
      stage(ck);
      __syncthreads();
#pragma unroll
      for (int gi = 0; gi < 2; ++gi) kloop(wv + 4 * gi, ck, acc2[gi]);
    }
    float* lf = (float*)smA;   // [192 n][32 m], addr = n*32 + ((mg ^ (n&7))<<2)
    float* out = (float*)outp;
    const int bb = m0 / HW_, hw0 = m0 - bb * HW_;
#pragma unroll
    for (int gi = 0; gi < 2; ++gi) {
      __syncthreads();
#pragma unroll
      for (int mt = 0; mt < 2; ++mt) {
        const int mg = mt * 4 + gh;
#pragma unroll
        for (int nt = 0; nt < NFR; ++nt) {
          const int nl = wv * 48 + nt * 16 + fr;       // 0..191
          const int c = gi * 192 + nl;
          f32x4 v = acc2[gi][mt][nt];
          const float bo = bias[c];
#pragma unroll
          for (int j = 0; j < 4; ++j)
            v[j] = v[j] + bo + resid[(size_t)(m0 + mt * 16 + (gh << 2) + j) * C_ + c];
          *(f32x4*)&lf[nl * 32 + ((mg ^ (nl & 7)) << 2)] = v;
        }
      }
      __syncthreads();
#pragma unroll
      for (int it = 0; it < 6; ++it) {
        const int nl = it * 32 + (tid >> 3);
        const int mg = tid & 7;
        f32x4 v = *(const f32x4*)&lf[nl * 32 + ((mg ^ (nl & 7)) << 2)];
        const int c = gi * 192 + nl;
        *(f32x4*)&out[((size_t)bb * C_ + c) * HW_ + hw0 + mg * 4] = v;
      }
    }
  }
}

// ---------------- multi-dilate local attention ----------------
__global__ __launch_bounds__(256)
void attn_kernel(const unsigned short* __restrict__ qkv,
                 const unsigned short* __restrict__ xn,
                 unsigned short* __restrict__ aout) {
  const int gid = blockIdx.x * 256 + threadIdx.x;
  const int n = gid / 12;
  const int r = gid - n * 12;
  const int dil = (r >> 2) + 1;
  const int b = n / HW_;
  const int hw = n - b * HW_;
  const int h = hw / W_;
  const int w = hw - h * W_;

  const size_t base = (size_t)n * C3_ + (size_t)r * HD_;
  float q[32];
  {
    const short8v* vp = (const short8v*)(qkv + base);
#pragma unroll
    for (int c8 = 0; c8 < 4; ++c8) {
      short8v v = vp[c8];
#pragma unroll
      for (int e = 0; e < 8; ++e) q[c8 * 8 + e] = bf2f((unsigned short)v[e]);
    }
  }

  float logit[9];
#pragma unroll
  for (int ti = 0; ti < 3; ++ti)
#pragma unroll
    for (int tj = 0; tj < 3; ++tj) {
      const int t = ti * 3 + tj;
      const int hn = h + (ti - 1) * dil, wn = w + (tj - 1) * dil;
      if ((unsigned)hn < 56u && (unsigned)wn < 56u) {
        const int nb = n + (ti - 1) * dil * W_ + (tj - 1) * dil;
        const short8v* kp = (const short8v*)(qkv + (size_t)nb * C3_ + C_ + (size_t)r * HD_);
        float dot = 0.f;
#pragma unroll
        for (int c8 = 0; c8 < 4; ++c8) {
          short8v v = kp[c8];
#pragma unroll
          for (int e = 0; e < 8; ++e) dot += q[c8 * 8 + e] * bf2f((unsigned short)v[e]);
        }
        logit[t] = dot * 0.17677669529663688f;  // 32^-0.5
      } else {
        logit[t] = 0.f;  // zero-padded taps participate with logit 0
      }
    }

  float mx = logit[0];
#pragma unroll
  for (int t = 1; t < 9; ++t) mx = fmaxf(mx, logit[t]);
  float wgt[9]; float se = 0.f;
#pragma unroll
  for (int t = 0; t < 9; ++t) { wgt[t] = __expf(logit[t] - mx); se += wgt[t]; }
  const float inv = 1.f / se;

  float acc[32];
#pragma unroll
  for (int c = 0; c < 32; ++c) acc[c] = 0.f;
#pragma unroll
  for (int ti = 0; ti < 3; ++ti)
#pragma unroll
    for (int tj = 0; tj < 3; ++tj) {
      const int t = ti * 3 + tj;
      const int hn = h + (ti - 1) * dil, wn = w + (tj - 1) * dil;
      if ((unsigned)hn < 56u && (unsigned)wn < 56u) {
        const int nb = n + (ti - 1) * dil * W_ + (tj - 1) * dil;
        const short8v* vp = (const short8v*)(qkv + (size_t)nb * C3_ + 2 * C_ + (size_t)r * HD_);
        const float wt = wgt[t];
#pragma unroll
        for (int c8 = 0; c8 < 4; ++c8) {
          short8v v = vp[c8];
#pragma unroll
          for (int e = 0; e < 8; ++e) acc[c8 * 8 + e] += wt * bf2f((unsigned short)v[e]);
        }
      }
    }

  const size_t obase = (size_t)n * C_ + (size_t)r * HD_;
  const short8v* xv = (const short8v*)(xn + obase);
  short8v ov[4];
#pragma unroll
  for (int c8 = 0; c8 < 4; ++c8) {
    short8v v = xv[c8];
#pragma unroll
    for (int e = 0; e < 8; ++e)
      ov[c8][e] = (short)f2bf(acc[c8 * 8 + e] * inv + bf2f((unsigned short)v[e]));
  }
  short8v* op = (short8v*)(aout + obase);
#pragma unroll
  for (int c8 = 0; c8 < 4; ++c8) op[c8] = ov[c8];
}

extern "C" void kernel_launch(void* const* d_in, const int* in_sizes, int n_in,
                              void* d_out, int out_size, void* d_ws, size_t ws_size,
                              hipStream_t stream) {
  const float* x = (const float*)d_in[0];
  const float* qkv_w = (const float*)d_in[1];
  const float* proj_w = (const float*)d_in[2];
  const float* proj_b = (const float*)d_in[3];
  const float* n1_g = (const float*)d_in[4];
  const float* n1_b = (const float*)d_in[5];
  const float* n2_g = (const float*)d_in[6];
  const float* n2_b = (const float*)d_in[7];
  const float* fc1_w = (const float*)d_in[8];
  const float* fc1_b = (const float*)d_in[9];
  const float* fc2_w = (const float*)d_in[10];
  const float* fc2_b = (const float*)d_in[11];

  char* ws = (char*)d_ws;
  float* xp = (float*)ws;                                        // [N,C] f32
  unsigned short* xn = (unsigned short*)(ws + 38535168);         // [N,C] bf16
  unsigned short* qkvb = (unsigned short*)(ws + 57802752);       // [N,1152] bf16
  unsigned short* abuf = (unsigned short*)(ws + 115605504);      // [N,C] bf16
  unsigned short* hbuf = qkvb;                                   // [N,1536] bf16 (reuse)
  unsigned short* wq = (unsigned short*)(ws + 134873088);        // bricked weights
  unsigned short* wp = wq + 442368;
  unsigned short* wf1 = wp + 147456;
  unsigned short* wf2 = wf1 + 589824;

  repack_w<<<6912, 256, 0, stream>>>(qkv_w, proj_w, fc1_w, fc2_w, wq);
  tpose_ln<<<392, 256, 0, stream>>>(x, xp, xn, n1_g, n1_b);
  gemmA<0, C3_, C_, 64><<<784, 256, 0, stream>>>(xn, wq, nullptr, nullptr, qkvb);
  attn_kernel<<<1176, 256, 0, stream>>>(qkvb, xn, abuf);
  gemmA<1, C_, C_, 48><<<784, 256, 0, stream>>>(abuf, wp, proj_b, xp, xp);
  ln_rows<<<6272, 256, 0, stream>>>(xp, xn, n2_g, n2_b);
  gemmA<2, HID_, C_, 64><<<784, 256, 0, stream>>>(xn, wf1, fc1_b, nullptr, hbuf);
  gemmA<3, C_, HID_, 48><<<784, 256, 0, stream>>>(hbuf, wf2, fc2_b, xp, d_out);
}

// Round 6
// 279.493 us; speedup vs baseline: 1.6881x; 1.6881x over previous
//
#include <hip/hip_runtime.h>
#include <hip/hip_bf16.h>

// LocalBlock: tpose+LN1 -> qkv GEMM -> multi-dilate attn(+xn) -> proj GEMM(+x, bf16 y)
//            -> LN2 -> fc1+gelu -> fc2(+y, transposed f32 out)
// GEMM: BM=128 BN=192 BK=32, 4 waves (wave-tile 64x96, acc[4][6]), LDS ring-4 (80KB),
//       counted vmcnt, 1 barrier/iter, conflict-free swizzle, XCD m-band swizzle.

#define B_   8
#define C_   384
#define W_   56
#define HW_  3136
#define N_   25088
#define HID_ 1536
#define C3_  1152

typedef __attribute__((ext_vector_type(8))) short short8v;
typedef __attribute__((ext_vector_type(4))) float f32x4;
typedef __attribute__((ext_vector_type(4))) unsigned short ushort4v;

__device__ __forceinline__ float bf2f(unsigned short u) {
  union { float f; unsigned u; } c; c.u = ((unsigned)u) << 16; return c.f;
}
__device__ __forceinline__ unsigned short f2bf(float f) {
  unsigned u = __float_as_uint(f);
  u = (u + 0x7FFFu + ((u >> 16) & 1u)) >> 16;
  return (unsigned short)u;
}

#define GLL(gsrc, ldst) __builtin_amdgcn_global_load_lds( \
    (const __attribute__((address_space(1))) void*)(gsrc), \
    (__attribute__((address_space(3))) void*)(ldst), 16, 0, 0)

// ---------------- weight fp32 -> bf16 (plain [n][k]) ----------------
__global__ void cvt_weights(const float* __restrict__ qw, const float* __restrict__ pw,
                            const float* __restrict__ f1, const float* __restrict__ f2,
                            unsigned short* __restrict__ o) {
  int i = blockIdx.x * 256 + threadIdx.x;
  if (i < 442368)        o[i] = f2bf(qw[i]);
  else if (i < 589824)   o[i] = f2bf(pw[i - 442368]);
  else if (i < 1179648)  o[i] = f2bf(f1[i - 589824]);
  else if (i < 1769472)  o[i] = f2bf(f2[i - 1179648]);
}

// ---------------- fused transpose + LN1: x[B,C,HW] -> xpb[N,C] bf16, xn[N,C] bf16 ---------
__global__ __launch_bounds__(256)
void tpose_ln(const float* __restrict__ x, unsigned short* __restrict__ xpb,
              unsigned short* __restrict__ xnb,
              const float* __restrict__ gam, const float* __restrict__ bet) {
  __shared__ float ft[64][385];
  __shared__ float mstat[64], rstat[64];
  const int tid = threadIdx.x;
  const int nb0 = blockIdx.x * 64;
  const int bb = nb0 / HW_, hw0 = nb0 - bb * HW_;
  const float* xb = x + (size_t)bb * C_ * HW_ + hw0;
#pragma unroll
  for (int p = 0; p < 24; ++p) {
    const int c = p * 16 + (tid >> 4);
    f32x4 v = *(const f32x4*)&xb[(size_t)c * HW_ + (tid & 15) * 4];
#pragma unroll
    for (int j = 0; j < 4; ++j) ft[(tid & 15) * 4 + j][c] = v[j];
  }
  __syncthreads();
  const int l16 = tid & 15, g16 = tid >> 4;
#pragma unroll
  for (int rr = 0; rr < 4; ++rr) {
    const int row = g16 * 4 + rr;
    float s = 0.f, ss = 0.f;
#pragma unroll
    for (int k2 = 0; k2 < 24; ++k2) { float v = ft[row][l16 + k2 * 16]; s += v; ss += v * v; }
    s += __shfl_xor(s, 8); ss += __shfl_xor(ss, 8);
    s += __shfl_xor(s, 4); ss += __shfl_xor(ss, 4);
    s += __shfl_xor(s, 2); ss += __shfl_xor(ss, 2);
    s += __shfl_xor(s, 1); ss += __shfl_xor(ss, 1);
    if (l16 == 0) {
      const float mean = s * (1.f / 384.f);
      const float var = ss * (1.f / 384.f) - mean * mean;
      mstat[row] = mean; rstat[row] = rsqrtf(var + 1e-5f);
    }
  }
  __syncthreads();
  const int row = tid >> 2, part = tid & 3;
  const float mean = mstat[row], rstd = rstat[row];
  unsigned short* xpr = xpb + (size_t)(nb0 + row) * C_ + part * 96;
  unsigned short* xr = xnb + (size_t)(nb0 + row) * C_ + part * 96;
#pragma unroll
  for (int q = 0; q < 12; ++q) {
    short8v oraw, oln;
#pragma unroll
    for (int e = 0; e < 8; ++e) {
      const int c = part * 96 + q * 8 + e;
      const float v = ft[row][c];
      oraw[e] = (short)f2bf(v);
      oln[e] = (short)f2bf((v - mean) * rstd * gam[c] + bet[c]);
    }
    *(short8v*)&xpr[q * 8] = oraw;
    *(short8v*)&xr[q * 8] = oln;
  }
}

// ---------------- row LayerNorm bf16 -> bf16 (LN2) ----------------
__global__ __launch_bounds__(256)
void ln_rows(const unsigned short* __restrict__ in, unsigned short* __restrict__ outb,
             const float* __restrict__ g, const float* __restrict__ bb) {
  const int row = blockIdx.x * 4 + (threadIdx.x >> 6);
  const int l = threadIdx.x & 63;
  float v[8]; float s = 0.f, ss = 0.f;
  if (l < 48) {
    short8v r = *(const short8v*)&in[(size_t)row * C_ + l * 8];
#pragma unroll
    for (int e = 0; e < 8; ++e) { v[e] = bf2f((unsigned short)r[e]); s += v[e]; ss += v[e] * v[e]; }
  }
#pragma unroll
  for (int off = 32; off; off >>= 1) { s += __shfl_xor(s, off); ss += __shfl_xor(ss, off); }
  const float mean = s * (1.f / 384.f);
  const float var = ss * (1.f / 384.f) - mean * mean;
  const float rstd = rsqrtf(var + 1e-5f);
  if (l < 48) {
    short8v o;
#pragma unroll
    for (int e = 0; e < 8; ++e) {
      const int c = l * 8 + e;
      o[e] = (short)f2bf((v[e] - mean) * rstd * g[c] + bb[c]);
    }
    *(short8v*)&outb[(size_t)row * C_ + l * 8] = o;
  }
}

// ---------------- GEMM: out[M,NOUT] = A[M,K] @ W[NOUT,K]^T ----------------
// MODE 0: bf16 out (qkv, no bias), SWAP orient, ushort4 stores
// MODE 1: bf16 out = resid(bf16) + v + bias (proj -> y), SWAP
// MODE 2: bf16 out = gelu(v + bias) (fc1), SWAP
// MODE 3: f32 d_out[B,C,HW] = resid(bf16) + v + bias, standard orient, LDS-transposed
template <int MODE, int NOUT, int K>
__global__ __launch_bounds__(256, 2)
void gemmN(const unsigned short* __restrict__ A, const unsigned short* __restrict__ Wt,
           const float* __restrict__ bias, const unsigned short* __restrict__ resid,
           void* __restrict__ outp) {
  constexpr bool SWAP = (MODE != 3);
  constexpr int KT = K / 32;
  __shared__ unsigned short sm[40960];   // 4 slots x 20 chunks x 512 ushorts = 80 KiB
  const int tid = threadIdx.x, l = tid & 63, wv = tid >> 6;
  const int wm = wv >> 1, wn = wv & 1;

  // XCD swizzle: m-major linearization, contiguous m-bands per XCD
  const int nx = gridDim.x;
  const int nwg = nx * gridDim.y;
  const int bid = blockIdx.y * nx + blockIdx.x;
  const int wg = (bid & 7) * (nwg >> 3) + (bid >> 3);
  const int m0 = (wg / nx) * 128, n0 = (wg % nx) * 192;

  // ---- staging: 20 chunks/slot (A:0..7 rows m0+16c.., B:8..19 rows n0+16(c-8)..)
  // lane l stages 16B: row = c*16 + (l>>2), colgroup = (l&3)^((l>>3)&3)  [inv swizzle]
  const int cg = (((l & 3) ^ ((l >> 3) & 3)) << 3);
  const unsigned short* gp[5];
  int gd[5];
#pragma unroll
  for (int i = 0; i < 5; ++i) {
    const int c = wv * 5 + i;
    const int rl = c * 16 + (l >> 2);
    gp[i] = (c < 8) ? A + (size_t)(m0 + rl) * K + cg
                    : Wt + (size_t)(n0 + (rl - 128)) * K + cg;
    gd[i] = c * 512 + l * 8;
  }
  auto stage = [&](int t) {
    const int sb = (t & 3) * 10240;
#pragma unroll
    for (int i = 0; i < 5; ++i) GLL(gp[i] + t * 32, &sm[sb + gd[i]]);
  };

  // ---- frag read offsets: slot-in-chunk s = fr*4 + (g ^ ((fr>>1)&3))
  const int fr = l & 15, g = l >> 4, g4 = g * 4;
  const int sA = (fr * 4 + (g ^ ((fr >> 1) & 3))) * 8;
  int aoff[4], boff[6];
#pragma unroll
  for (int mt = 0; mt < 4; ++mt) aoff[mt] = (wm * 4 + mt) * 512 + sA;
#pragma unroll
  for (int nt = 0; nt < 6; ++nt) boff[nt] = (8 + wn * 6 + nt) * 512 + sA;

  f32x4 acc[4][6] = {};

  stage(0); stage(1); stage(2);
  for (int t = 0; t < KT; ++t) {
    const int rem = KT - t;
    if (rem > 2)       asm volatile("s_waitcnt vmcnt(10)" ::: "memory");
    else if (rem == 2) asm volatile("s_waitcnt vmcnt(5)" ::: "memory");
    else               asm volatile("s_waitcnt vmcnt(0)" ::: "memory");
    __builtin_amdgcn_sched_barrier(0);
    __builtin_amdgcn_s_barrier();
    __builtin_amdgcn_sched_barrier(0);
    if (t + 3 < KT) stage(t + 3);
    __builtin_amdgcn_sched_barrier(0);
    const int sb = (t & 3) * 10240;
    short8v av[4], bv[6];
#pragma unroll
    for (int mt = 0; mt < 4; ++mt) av[mt] = *(const short8v*)&sm[sb + aoff[mt]];
#pragma unroll
    for (int nt = 0; nt < 6; ++nt) bv[nt] = *(const short8v*)&sm[sb + boff[nt]];
    __builtin_amdgcn_s_setprio(1);
#pragma unroll
    for (int mt = 0; mt < 4; ++mt)
#pragma unroll
      for (int nt = 0; nt < 6; ++nt)
        acc[mt][nt] = SWAP
          ? __builtin_amdgcn_mfma_f32_16x16x32_bf16(bv[nt], av[mt], acc[mt][nt], 0, 0, 0)
          : __builtin_amdgcn_mfma_f32_16x16x32_bf16(av[mt], bv[nt], acc[mt][nt], 0, 0, 0);
    __builtin_amdgcn_s_setprio(0);
    __builtin_amdgcn_sched_barrier(0);
  }

  if constexpr (SWAP) {
    // lane: m = m0 + wm*64 + mt*16 + fr ; n = n0 + wn*96 + nt*16 + g4 + j
    unsigned short* op = (unsigned short*)outp;
#pragma unroll
    for (int mt = 0; mt < 4; ++mt) {
      const int m = m0 + wm * 64 + mt * 16 + fr;
#pragma unroll
      for (int nt = 0; nt < 6; ++nt) {
        const int n = n0 + wn * 96 + nt * 16 + g4;
        f32x4 v = acc[mt][nt];
        ushort4v pk;
        if constexpr (MODE == 2) {
          const f32x4 b4 = *(const f32x4*)&bias[n];
#pragma unroll
          for (int j = 0; j < 4; ++j) {
            const float xv = v[j] + b4[j];
            pk[j] = f2bf(0.5f * xv * (1.f + erff(xv * 0.70710678118f)));
          }
        } else if constexpr (MODE == 1) {
          const f32x4 b4 = *(const f32x4*)&bias[n];
          const ushort4v r4 = *(const ushort4v*)&resid[(size_t)m * C_ + n];
#pragma unroll
          for (int j = 0; j < 4; ++j) pk[j] = f2bf(v[j] + b4[j] + bf2f(r4[j]));
        } else {
#pragma unroll
          for (int j = 0; j < 4; ++j) pk[j] = f2bf(v[j]);
        }
        *(ushort4v*)&op[(size_t)m * NOUT + n] = pk;
      }
    }
  } else {
    // MODE 3: lane: m = m0 + wm*64 + mt*16 + g4 + j ; c = n0 + p*96 + nt*16 + fr
    __syncthreads();
    float* lf = (float*)sm;     // [96 c'][32 u] f32x4-swizzled: idx = c'*128 + ((u^(c'&7))<<2)
    float* out = (float*)outp;
#pragma unroll
    for (int p = 0; p < 2; ++p) {
      if (wn == p) {
#pragma unroll
        for (int mt = 0; mt < 4; ++mt) {
          const int u = wm * 16 + mt * 4 + g;
#pragma unroll
          for (int nt = 0; nt < 6; ++nt) {
            const int cl = nt * 16 + fr;
            const int cgl = n0 + p * 96 + cl;
            const float bo = bias[cgl];
            f32x4 v = acc[mt][nt];
#pragma unroll
            for (int j = 0; j < 4; ++j)
              v[j] = v[j] + bo + bf2f(resid[(size_t)(m0 + u * 4 + j) * C_ + cgl]);
            *(f32x4*)&lf[cl * 128 + ((u ^ (cl & 7)) << 2)] = v;
          }
        }
      }
      __syncthreads();
#pragma unroll
      for (int rr = 0; rr < 3; ++rr) {
        const int cl = rr * 32 + (tid >> 3);
        const int cgl = n0 + p * 96 + cl;
#pragma unroll
        for (int it = 0; it < 4; ++it) {
          const int u = (tid & 7) + it * 8;
          f32x4 v = *(const f32x4*)&lf[cl * 128 + ((u ^ (cl & 7)) << 2)];
          const int mg = m0 + u * 4;
          const int bb = mg / HW_, hw = mg - bb * HW_;
          *(f32x4*)&out[((size_t)bb * C_ + cgl) * HW_ + hw] = v;
        }
      }
      __syncthreads();
    }
  }
}

// ---------------- multi-dilate local attention (+xn) ----------------
__global__ __launch_bounds__(256)
void attn_kernel(const unsigned short* __restrict__ qkv,
                 const unsigned short* __restrict__ xn,
                 unsigned short* __restrict__ aout) {
  const int gid = blockIdx.x * 256 + threadIdx.x;
  const int n = gid / 12;
  const int r = gid - n * 12;
  const int dil = (r >> 2) + 1;
  const int b = n / HW_;
  const int hw = n - b * HW_;
  const int h = hw / W_;
  const int w = hw - h * W_;

  const size_t base = (size_t)n * C3_ + (size_t)r * 32;
  float q[32];
  {
    const short8v* vp = (const short8v*)(qkv + base);
#pragma unroll
    for (int c8 = 0; c8 < 4; ++c8) {
      short8v v = vp[c8];
#pragma unroll
      for (int e = 0; e < 8; ++e) q[c8 * 8 + e] = bf2f((unsigned short)v[e]);
    }
  }

  float logit[9];
#pragma unroll
  for (int ti = 0; ti < 3; ++ti)
#pragma unroll
    for (int tj = 0; tj < 3; ++tj) {
      const int t = ti * 3 + tj;
      const int hn = h + (ti - 1) * dil, wn = w + (tj - 1) * dil;
      if ((unsigned)hn < 56u && (unsigned)wn < 56u) {
        const int nb = n + (ti - 1) * dil * W_ + (tj - 1) * dil;
        const short8v* kp = (const short8v*)(qkv + (size_t)nb * C3_ + C_ + (size_t)r * 32);
        float dot = 0.f;
#pragma unroll
        for (int c8 = 0; c8 < 4; ++c8) {
          short8v v = kp[c8];
#pragma unroll
          for (int e = 0; e < 8; ++e) dot += q[c8 * 8 + e] * bf2f((unsigned short)v[e]);
        }
        logit[t] = dot * 0.17677669529663688f;
      } else {
        logit[t] = 0.f;  // zero-padded taps participate with logit 0
      }
    }

  float mx = logit[0];
#pragma unroll
  for (int t = 1; t < 9; ++t) mx = fmaxf(mx, logit[t]);
  float wgt[9]; float se = 0.f;
#pragma unroll
  for (int t = 0; t < 9; ++t) { wgt[t] = __expf(logit[t] - mx); se += wgt[t]; }
  const float inv = 1.f / se;

  float acc[32];
#pragma unroll
  for (int c = 0; c < 32; ++c) acc[c] = 0.f;
#pragma unroll
  for (int ti = 0; ti < 3; ++ti)
#pragma unroll
    for (int tj = 0; tj < 3; ++tj) {
      const int t = ti * 3 + tj;
      const int hn = h + (ti - 1) * dil, wn = w + (tj - 1) * dil;
      if ((unsigned)hn < 56u && (unsigned)wn < 56u) {
        const int nb = n + (ti - 1) * dil * W_ + (tj - 1) * dil;
        const short8v* vp = (const short8v*)(qkv + (size_t)nb * C3_ + 2 * C_ + (size_t)r * 32);
        const float wt = wgt[t];
#pragma unroll
        for (int c8 = 0; c8 < 4; ++c8) {
          short8v v = vp[c8];
#pragma unroll
          for (int e = 0; e < 8; ++e) acc[c8 * 8 + e] += wt * bf2f((unsigned short)v[e]);
        }
      }
    }

  const size_t obase = (size_t)n * C_ + (size_t)r * 32;
  const short8v* xv = (const short8v*)(xn + obase);
  short8v ov[4];
#pragma unroll
  for (int c8 = 0; c8 < 4; ++c8) {
    short8v v = xv[c8];
#pragma unroll
    for (int e = 0; e < 8; ++e)
      ov[c8][e] = (short)f2bf(acc[c8 * 8 + e] * inv + bf2f((unsigned short)v[e]));
  }
  short8v* op = (short8v*)(aout + obase);
#pragma unroll
  for (int c8 = 0; c8 < 4; ++c8) op[c8] = ov[c8];
}

extern "C" void kernel_launch(void* const* d_in, const int* in_sizes, int n_in,
                              void* d_out, int out_size, void* d_ws, size_t ws_size,
                              hipStream_t stream) {
  const float* x = (const float*)d_in[0];
  const float* qkv_w = (const float*)d_in[1];
  const float* proj_w = (const float*)d_in[2];
  const float* proj_b = (const float*)d_in[3];
  const float* n1_g = (const float*)d_in[4];
  const float* n1_b = (const float*)d_in[5];
  const float* n2_g = (const float*)d_in[6];
  const float* n2_b = (const float*)d_in[7];
  const float* fc1_w = (const float*)d_in[8];
  const float* fc1_b = (const float*)d_in[9];
  const float* fc2_w = (const float*)d_in[10];
  const float* fc2_b = (const float*)d_in[11];

  char* ws = (char*)d_ws;
  unsigned short* xpb = (unsigned short*)ws;                     // [N,C] bf16 (x transposed)
  unsigned short* xn = (unsigned short*)(ws + 19267584);         // [N,C] bf16 (LN1 out / LN2 out)
  unsigned short* qkvb = (unsigned short*)(ws + 38535168);       // [N,1152] bf16
  unsigned short* abuf = (unsigned short*)(ws + 96337920);       // [N,C] bf16
  unsigned short* y = (unsigned short*)(ws + 115605504);         // [N,C] bf16 residual stream
  unsigned short* hbuf = qkvb;                                   // [N,1536] bf16 (reuse qkv+abuf)
  unsigned short* wq = (unsigned short*)(ws + 134873088);        // weights bf16 [n][k]
  unsigned short* wp = wq + 442368;
  unsigned short* wf1 = wp + 147456;
  unsigned short* wf2 = wf1 + 589824;

  cvt_weights<<<6912, 256, 0, stream>>>(qkv_w, proj_w, fc1_w, fc2_w, wq);
  tpose_ln<<<392, 256, 0, stream>>>(x, xpb, xn, n1_g, n1_b);
  gemmN<0, C3_, C_><<<dim3(6, 196), 256, 0, stream>>>(xn, wq, nullptr, nullptr, qkvb);
  attn_kernel<<<1176, 256, 0, stream>>>(qkvb, xn, abuf);
  gemmN<1, C_, C_><<<dim3(2, 196), 256, 0, stream>>>(abuf, wp, proj_b, xpb, y);
  ln_rows<<<6272, 256, 0, stream>>>(y, xn, n2_g, n2_b);
  gemmN<2, HID_, C_><<<dim3(8, 196), 256, 0, stream>>>(xn, wf1, fc1_b, nullptr, hbuf);
  gemmN<3, C_, HID_><<<dim3(2, 196), 256, 0, stream>>>(hbuf, wf2, fc2_b, y, d_out);
}

// Round 7
// 269.270 us; speedup vs baseline: 1.7522x; 1.0380x over previous
//
#include <hip/hip_runtime.h>
#include <hip/hip_bf16.h>

// LocalBlock: tpose+LN1 -> qkv GEMM -> multi-dilate attn(+xn) -> proj GEMM(+x, bf16 y)
//            -> LN2 -> fc1+gelu -> fc2(+y, transposed f32 out)
// GEMM: BM=128 BN=192 BK=32, 512 thr (8 waves 2m x 4n, wave-tile 64x48, acc[4][3]),
//       LDS ring-4 x 20KB = 80KB (2 blocks/CU = 16 waves), counted vmcnt, 1 barrier/iter,
//       conflict-free swizzle (round-6-verified), bijective XCD m-band swizzle.

#define B_   8
#define C_   384
#define W_   56
#define HW_  3136
#define N_   25088
#define HID_ 1536
#define C3_  1152

typedef __attribute__((ext_vector_type(8))) short short8v;
typedef __attribute__((ext_vector_type(4))) float f32x4;
typedef __attribute__((ext_vector_type(4))) unsigned short ushort4v;

__device__ __forceinline__ float bf2f(unsigned short u) {
  union { float f; unsigned u; } c; c.u = ((unsigned)u) << 16; return c.f;
}
__device__ __forceinline__ unsigned short f2bf(float f) {
  unsigned u = __float_as_uint(f);
  u = (u + 0x7FFFu + ((u >> 16) & 1u)) >> 16;
  return (unsigned short)u;
}

#define GLL(gsrc, ldst) __builtin_amdgcn_global_load_lds( \
    (const __attribute__((address_space(1))) void*)(gsrc), \
    (__attribute__((address_space(3))) void*)(ldst), 16, 0, 0)

// ---------------- weight fp32 -> bf16 (plain [n][k]) ----------------
__global__ void cvt_weights(const float* __restrict__ qw, const float* __restrict__ pw,
                            const float* __restrict__ f1, const float* __restrict__ f2,
                            unsigned short* __restrict__ o) {
  int i = blockIdx.x * 256 + threadIdx.x;
  if (i < 442368)        o[i] = f2bf(qw[i]);
  else if (i < 589824)   o[i] = f2bf(pw[i - 442368]);
  else if (i < 1179648)  o[i] = f2bf(f1[i - 589824]);
  else if (i < 1769472)  o[i] = f2bf(f2[i - 1179648]);
}

// ---------------- fused transpose + LN1: x[B,C,HW] -> xpb[N,C] bf16, xn[N,C] bf16 ---------
__global__ __launch_bounds__(256)
void tpose_ln(const float* __restrict__ x, unsigned short* __restrict__ xpb,
              unsigned short* __restrict__ xnb,
              const float* __restrict__ gam, const float* __restrict__ bet) {
  __shared__ float ft[64][385];
  __shared__ float mstat[64], rstat[64];
  const int tid = threadIdx.x;
  const int nb0 = blockIdx.x * 64;
  const int bb = nb0 / HW_, hw0 = nb0 - bb * HW_;
  const float* xb = x + (size_t)bb * C_ * HW_ + hw0;
#pragma unroll
  for (int p = 0; p < 24; ++p) {
    const int c = p * 16 + (tid >> 4);
    f32x4 v = *(const f32x4*)&xb[(size_t)c * HW_ + (tid & 15) * 4];
#pragma unroll
    for (int j = 0; j < 4; ++j) ft[(tid & 15) * 4 + j][c] = v[j];
  }
  __syncthreads();
  const int l16 = tid & 15, g16 = tid >> 4;
#pragma unroll
  for (int rr = 0; rr < 4; ++rr) {
    const int row = g16 * 4 + rr;
    float s = 0.f, ss = 0.f;
#pragma unroll
    for (int k2 = 0; k2 < 24; ++k2) { float v = ft[row][l16 + k2 * 16]; s += v; ss += v * v; }
    s += __shfl_xor(s, 8); ss += __shfl_xor(ss, 8);
    s += __shfl_xor(s, 4); ss += __shfl_xor(ss, 4);
    s += __shfl_xor(s, 2); ss += __shfl_xor(ss, 2);
    s += __shfl_xor(s, 1); ss += __shfl_xor(ss, 1);
    if (l16 == 0) {
      const float mean = s * (1.f / 384.f);
      const float var = ss * (1.f / 384.f) - mean * mean;
      mstat[row] = mean; rstat[row] = rsqrtf(var + 1e-5f);
    }
  }
  __syncthreads();
  const int row = tid >> 2, part = tid & 3;
  const float mean = mstat[row], rstd = rstat[row];
  unsigned short* xpr = xpb + (size_t)(nb0 + row) * C_ + part * 96;
  unsigned short* xr = xnb + (size_t)(nb0 + row) * C_ + part * 96;
#pragma unroll
  for (int q = 0; q < 12; ++q) {
    short8v oraw, oln;
#pragma unroll
    for (int e = 0; e < 8; ++e) {
      const int c = part * 96 + q * 8 + e;
      const float v = ft[row][c];
      oraw[e] = (short)f2bf(v);
      oln[e] = (short)f2bf((v - mean) * rstd * gam[c] + bet[c]);
    }
    *(short8v*)&xpr[q * 8] = oraw;
    *(short8v*)&xr[q * 8] = oln;
  }
}

// ---------------- row LayerNorm bf16 -> bf16 (LN2) ----------------
__global__ __launch_bounds__(256)
void ln_rows(const unsigned short* __restrict__ in, unsigned short* __restrict__ outb,
             const float* __restrict__ g, const float* __restrict__ bb) {
  const int row = blockIdx.x * 4 + (threadIdx.x >> 6);
  const int l = threadIdx.x & 63;
  float v[8]; float s = 0.f, ss = 0.f;
  if (l < 48) {
    short8v r = *(const short8v*)&in[(size_t)row * C_ + l * 8];
#pragma unroll
    for (int e = 0; e < 8; ++e) { v[e] = bf2f((unsigned short)r[e]); s += v[e]; ss += v[e] * v[e]; }
  }
#pragma unroll
  for (int off = 32; off; off >>= 1) { s += __shfl_xor(s, off); ss += __shfl_xor(ss, off); }
  const float mean = s * (1.f / 384.f);
  const float var = ss * (1.f / 384.f) - mean * mean;
  const float rstd = rsqrtf(var + 1e-5f);
  if (l < 48) {
    short8v o;
#pragma unroll
    for (int e = 0; e < 8; ++e) {
      const int c = l * 8 + e;
      o[e] = (short)f2bf((v[e] - mean) * rstd * g[c] + bb[c]);
    }
    *(short8v*)&outb[(size_t)row * C_ + l * 8] = o;
  }
}

// ---------------- GEMM: out[M,NOUT] = A[M,K] @ W[NOUT,K]^T ----------------
// MODE 0: bf16 out (qkv, no bias), SWAP orient           MODE 1: bf16 out = resid + v + bias
// MODE 2: bf16 out = gelu(v + bias) (fc1), SWAP          MODE 3: f32 d_out[B,C,HW] transposed
template <int MODE, int NOUT, int K>
__global__ __launch_bounds__(512, 4)
void gemmW(const unsigned short* __restrict__ A, const unsigned short* __restrict__ Wt,
           const float* __restrict__ bias, const unsigned short* __restrict__ resid,
           void* __restrict__ outp) {
  constexpr bool SWAP = (MODE != 3);
  constexpr int KT = K / 32;
  constexpr int SLOTU = 320 * 32;            // (128+192) rows x 32 cols ushorts = 20KB
  __shared__ unsigned short sm[4 * SLOTU];   // 80 KiB ring-4
  const int tid = threadIdx.x, l = tid & 63, wv = tid >> 6;
  const int wm = wv >> 2, wn = wv & 3;

  // bijective XCD swizzle (nwg % 8 == 0 for all grids), m-band contiguous per XCD
  const int nx = gridDim.x;
  const int nwg = nx * gridDim.y;
  const int bid = blockIdx.y * nx + blockIdx.x;
  const int wg = (bid & 7) * (nwg >> 3) + (bid >> 3);
  const int m0 = (wg / nx) * 128, n0 = (wg % nx) * 192;

  // staging: 20 chunks/stage (A: 0..7 = rows m0+16c.., B: 8..19 = rows n0+16(c-8)..)
  // lane l: row-in-chunk = l>>2, col-group src = (l&3)^((l>>3)&3)  [inverse swizzle]
  const int cpw = (wv >= 4) ? 2 : 3;         // chunks per wave (20 = 4*3 + 4*2)
  const int cg = (((l & 3) ^ ((l >> 3) & 3)) << 3);
  const unsigned short* gp[3]; int gd[3];
#pragma unroll
  for (int i = 0; i < 3; ++i) {
    const int ci = wv + 8 * i;               // i=2 only used when cpw==3 (ci<=19)
    const int rl = (ci < 20 ? ci : 0) * 16 + (l >> 2);
    gp[i] = (ci < 8) ? A + (size_t)(m0 + rl) * K + cg
                     : Wt + (size_t)(n0 + (rl - 128)) * K + cg;
    gd[i] = (ci < 20 ? ci : 0) * 512 + l * 8;
  }
  auto stage = [&](int t) {
    const int sb = (t & 3) * SLOTU;
    for (int i = 0; i < cpw; ++i) GLL(gp[i] + t * 32, &sm[sb + gd[i]]);
  };

  // fragment read offsets (swizzled): s = fr*4 + (g ^ ((fr>>1)&3))
  const int fr = l & 15, g = l >> 4, g4 = g * 4;
  const int sfr = (fr * 4 + (g ^ ((fr >> 1) & 3))) * 8;
  int aoff[4], boff[3];
#pragma unroll
  for (int mt = 0; mt < 4; ++mt) aoff[mt] = (wm * 4 + mt) * 512 + sfr;
#pragma unroll
  for (int nt = 0; nt < 3; ++nt) boff[nt] = (8 + wn * 3 + nt) * 512 + sfr;

  f32x4 acc[4][3] = {};

  stage(0); stage(1); stage(2);
  for (int t = 0; t < KT; ++t) {
    const int rem = KT - t;
    if (rem > 2) {
      if (cpw == 3) asm volatile("s_waitcnt vmcnt(6)" ::: "memory");
      else          asm volatile("s_waitcnt vmcnt(4)" ::: "memory");
    } else if (rem == 2) {
      if (cpw == 3) asm volatile("s_waitcnt vmcnt(3)" ::: "memory");
      else          asm volatile("s_waitcnt vmcnt(2)" ::: "memory");
    } else {
      asm volatile("s_waitcnt vmcnt(0)" ::: "memory");
    }
    __builtin_amdgcn_sched_barrier(0);
    __builtin_amdgcn_s_barrier();
    __builtin_amdgcn_sched_barrier(0);
    if (t + 3 < KT) stage(t + 3);            // slot (t+3)&3 freed at end of iter t-1
    __builtin_amdgcn_sched_barrier(0);
    const int sb = (t & 3) * SLOTU;
    short8v av[4], bv[3];
#pragma unroll
    for (int mt = 0; mt < 4; ++mt) av[mt] = *(const short8v*)&sm[sb + aoff[mt]];
#pragma unroll
    for (int nt = 0; nt < 3; ++nt) bv[nt] = *(const short8v*)&sm[sb + boff[nt]];
    __builtin_amdgcn_s_setprio(1);
#pragma unroll
    for (int mt = 0; mt < 4; ++mt)
#pragma unroll
      for (int nt = 0; nt < 3; ++nt)
        acc[mt][nt] = SWAP
          ? __builtin_amdgcn_mfma_f32_16x16x32_bf16(bv[nt], av[mt], acc[mt][nt], 0, 0, 0)
          : __builtin_amdgcn_mfma_f32_16x16x32_bf16(av[mt], bv[nt], acc[mt][nt], 0, 0, 0);
    __builtin_amdgcn_s_setprio(0);
    __builtin_amdgcn_sched_barrier(0);
  }

  if constexpr (SWAP) {
    // lane: m = m0 + wm*64 + mt*16 + fr ; n = n0 + wn*48 + nt*16 + g4 + j
    unsigned short* op = (unsigned short*)outp;
#pragma unroll
    for (int mt = 0; mt < 4; ++mt) {
      const int m = m0 + wm * 64 + mt * 16 + fr;
#pragma unroll
      for (int nt = 0; nt < 3; ++nt) {
        const int n = n0 + wn * 48 + nt * 16 + g4;
        f32x4 v = acc[mt][nt];
        ushort4v pk;
        if constexpr (MODE == 2) {
          const f32x4 b4 = *(const f32x4*)&bias[n];
#pragma unroll
          for (int j = 0; j < 4; ++j) {
            const float xv = v[j] + b4[j];
            pk[j] = f2bf(0.5f * xv * (1.f + erff(xv * 0.70710678118f)));
          }
        } else if constexpr (MODE == 1) {
          const f32x4 b4 = *(const f32x4*)&bias[n];
          const ushort4v r4 = *(const ushort4v*)&resid[(size_t)m * C_ + n];
#pragma unroll
          for (int j = 0; j < 4; ++j) pk[j] = f2bf(v[j] + b4[j] + bf2f(r4[j]));
        } else {
#pragma unroll
          for (int j = 0; j < 4; ++j) pk[j] = f2bf(v[j]);
        }
        *(ushort4v*)&op[(size_t)m * NOUT + n] = pk;
      }
    }
  } else {
    // MODE 3: lane: m = m0 + wm*64 + mt*16 + g4 + j ; c = n0 + wn*48 + nt*16 + fr
    __syncthreads();
    float* lf = (float*)sm;     // [96 c'][32 u] swizzled: idx = c'*128 + ((u^(c'&7))<<2)
    float* out = (float*)outp;
#pragma unroll
    for (int p = 0; p < 2; ++p) {
      if ((wn >> 1) == p) {
#pragma unroll
        for (int mt = 0; mt < 4; ++mt) {
          const int u = wm * 16 + mt * 4 + g;
#pragma unroll
          for (int nt = 0; nt < 3; ++nt) {
            const int cl = (wn & 1) * 48 + nt * 16 + fr;
            const int cgl = n0 + p * 96 + cl;
            const float bo = bias[cgl];
            f32x4 v = acc[mt][nt];
#pragma unroll
            for (int j = 0; j < 4; ++j)
              v[j] = v[j] + bo + bf2f(resid[(size_t)(m0 + u * 4 + j) * C_ + cgl]);
            *(f32x4*)&lf[cl * 128 + ((u ^ (cl & 7)) << 2)] = v;
          }
        }
      }
      __syncthreads();
#pragma unroll
      for (int i = 0; i < 6; ++i) {
        const int slot = tid + 512 * i;      // 96 cols x 32 row-chunks = 3072 slots
        const int u = slot & 31, cl = slot >> 5;
        f32x4 v = *(const f32x4*)&lf[cl * 128 + ((u ^ (cl & 7)) << 2)];
        const int cgl = n0 + p * 96 + cl;
        const int mg = m0 + u * 4;
        const int bb = mg / HW_, hw = mg - bb * HW_;
        *(f32x4*)&out[((size_t)bb * C_ + cgl) * HW_ + hw] = v;
      }
      __syncthreads();
    }
  }
}

// ---------------- multi-dilate local attention (+xn) ----------------
__global__ __launch_bounds__(256)
void attn_kernel(const unsigned short* __restrict__ qkv,
                 const unsigned short* __restrict__ xn,
                 unsigned short* __restrict__ aout) {
  const int gid = blockIdx.x * 256 + threadIdx.x;
  const int n = gid / 12;
  const int r = gid - n * 12;
  const int dil = (r >> 2) + 1;
  const int b = n / HW_;
  const int hw = n - b * HW_;
  const int h = hw / W_;
  const int w = hw - h * W_;

  const size_t base = (size_t)n * C3_ + (size_t)r * 32;
  float q[32];
  {
    const short8v* vp = (const short8v*)(qkv + base);
#pragma unroll
    for (int c8 = 0; c8 < 4; ++c8) {
      short8v v = vp[c8];
#pragma unroll
      for (int e = 0; e < 8; ++e) q[c8 * 8 + e] = bf2f((unsigned short)v[e]);
    }
  }

  float logit[9];
#pragma unroll
  for (int ti = 0; ti < 3; ++ti)
#pragma unroll
    for (int tj = 0; tj < 3; ++tj) {
      const int t = ti * 3 + tj;
      const int hn = h + (ti - 1) * dil, wn = w + (tj - 1) * dil;
      if ((unsigned)hn < 56u && (unsigned)wn < 56u) {
        const int nb = n + (ti - 1) * dil * W_ + (tj - 1) * dil;
        const short8v* kp = (const short8v*)(qkv + (size_t)nb * C3_ + C_ + (size_t)r * 32);
        float dot = 0.f;
#pragma unroll
        for (int c8 = 0; c8 < 4; ++c8) {
          short8v v = kp[c8];
#pragma unroll
          for (int e = 0; e < 8; ++e) dot += q[c8 * 8 + e] * bf2f((unsigned short)v[e]);
        }
        logit[t] = dot * 0.17677669529663688f;
      } else {
        logit[t] = 0.f;  // zero-padded taps participate with logit 0
      }
    }

  float mx = logit[0];
#pragma unroll
  for (int t = 1; t < 9; ++t) mx = fmaxf(mx, logit[t]);
  float wgt[9]; float se = 0.f;
#pragma unroll
  for (int t = 0; t < 9; ++t) { wgt[t] = __expf(logit[t] - mx); se += wgt[t]; }
  const float inv = 1.f / se;

  float acc[32];
#pragma unroll
  for (int c = 0; c < 32; ++c) acc[c] = 0.f;
#pragma unroll
  for (int ti = 0; ti < 3; ++ti)
#pragma unroll
    for (int tj = 0; tj < 3; ++tj) {
      const int t = ti * 3 + tj;
      const int hn = h + (ti - 1) * dil, wn = w + (tj - 1) * dil;
      if ((unsigned)hn < 56u && (unsigned)wn < 56u) {
        const int nb = n + (ti - 1) * dil * W_ + (tj - 1) * dil;
        const short8v* vp = (const short8v*)(qkv + (size_t)nb * C3_ + 2 * C_ + (size_t)r * 32);
        const float wt = wgt[t];
#pragma unroll
        for (int c8 = 0; c8 < 4; ++c8) {
          short8v v = vp[c8];
#pragma unroll
          for (int e = 0; e < 8; ++e) acc[c8 * 8 + e] += wt * bf2f((unsigned short)v[e]);
        }
      }
    }

  const size_t obase = (size_t)n * C_ + (size_t)r * 32;
  const short8v* xv = (const short8v*)(xn + obase);
  short8v ov[4];
#pragma unroll
  for (int c8 = 0; c8 < 4; ++c8) {
    short8v v = xv[c8];
#pragma unroll
    for (int e = 0; e < 8; ++e)
      ov[c8][e] = (short)f2bf(acc[c8 * 8 + e] * inv + bf2f((unsigned short)v[e]));
  }
  short8v* op = (short8v*)(aout + obase);
#pragma unroll
  for (int c8 = 0; c8 < 4; ++c8) op[c8] = ov[c8];
}

extern "C" void kernel_launch(void* const* d_in, const int* in_sizes, int n_in,
                              void* d_out, int out_size, void* d_ws, size_t ws_size,
                              hipStream_t stream) {
  const float* x = (const float*)d_in[0];
  const float* qkv_w = (const float*)d_in[1];
  const float* proj_w = (const float*)d_in[2];
  const float* proj_b = (const float*)d_in[3];
  const float* n1_g = (const float*)d_in[4];
  const float* n1_b = (const float*)d_in[5];
  const float* n2_g = (const float*)d_in[6];
  const float* n2_b = (const float*)d_in[7];
  const float* fc1_w = (const float*)d_in[8];
  const float* fc1_b = (const float*)d_in[9];
  const float* fc2_w = (const float*)d_in[10];
  const float* fc2_b = (const float*)d_in[11];

  char* ws = (char*)d_ws;
  unsigned short* xpb = (unsigned short*)ws;                     // [N,C] bf16 (x transposed)
  unsigned short* xn = (unsigned short*)(ws + 19267584);         // [N,C] bf16 (LN1/LN2 out)
  unsigned short* qkvb = (unsigned short*)(ws + 38535168);       // [N,1152] bf16
  unsigned short* abuf = (unsigned short*)(ws + 96337920);       // [N,C] bf16
  unsigned short* y = (unsigned short*)(ws + 115605504);         // [N,C] bf16 residual stream
  unsigned short* hbuf = qkvb;                                   // [N,1536] bf16 (reuse)
  unsigned short* wq = (unsigned short*)(ws + 134873088);        // weights bf16 [n][k]
  unsigned short* wp = wq + 442368;
  unsigned short* wf1 = wp + 147456;
  unsigned short* wf2 = wf1 + 589824;

  cvt_weights<<<6912, 256, 0, stream>>>(qkv_w, proj_w, fc1_w, fc2_w, wq);
  tpose_ln<<<392, 256, 0, stream>>>(x, xpb, xn, n1_g, n1_b);
  gemmW<0, C3_, C_><<<dim3(6, 196), 512, 0, stream>>>(xn, wq, nullptr, nullptr, qkvb);
  attn_kernel<<<1176, 256, 0, stream>>>(qkvb, xn, abuf);
  gemmW<1, C_, C_><<<dim3(2, 196), 512, 0, stream>>>(abuf, wp, proj_b, xpb, y);
  ln_rows<<<6272, 256, 0, stream>>>(y, xn, n2_g, n2_b);
  gemmW<2, HID_, C_><<<dim3(8, 196), 512, 0, stream>>>(xn, wf1, fc1_b, nullptr, hbuf);
  gemmW<3, C_, HID_><<<dim3(2, 196), 512, 0, stream>>>(hbuf, wf2, fc2_b, y, d_out);
}

// Round 8
// 257.255 us; speedup vs baseline: 1.8340x; 1.0467x over previous
//
#include <hip/hip_runtime.h>
#include <hip/hip_bf16.h>

// LocalBlock: tpose+LN1 -> qkv GEMM -> multi-dilate attn(+xn) -> proj GEMM(+x, bf16 y)
//            -> LN2 -> fc1+gelu -> fc2(+y, transposed f32 out)
// GEMM: BM=128 BN=192 BK=32, 512 thr (8 waves 2m x 4n, wave-tile 64x48, acc[4][3]),
//       LDS ring-4 x 20KB = 80KB, counted vmcnt, 1 barrier/iter, conflict-free swizzle,
//       bijective XCD m-band swizzle. NEW: all epilogues store coalesced via LDS.

#define B_   8
#define C_   384
#define W_   56
#define HW_  3136
#define N_   25088
#define HID_ 1536
#define C3_  1152

typedef __attribute__((ext_vector_type(8))) short short8v;
typedef __attribute__((ext_vector_type(4))) float f32x4;
typedef __attribute__((ext_vector_type(4))) unsigned short ushort4v;

__device__ __forceinline__ float bf2f(unsigned short u) {
  union { float f; unsigned u; } c; c.u = ((unsigned)u) << 16; return c.f;
}
__device__ __forceinline__ unsigned short f2bf(float f) {
  unsigned u = __float_as_uint(f);
  u = (u + 0x7FFFu + ((u >> 16) & 1u)) >> 16;
  return (unsigned short)u;
}

#define GLL(gsrc, ldst) __builtin_amdgcn_global_load_lds( \
    (const __attribute__((address_space(1))) void*)(gsrc), \
    (__attribute__((address_space(3))) void*)(ldst), 16, 0, 0)

// ---------------- weight fp32 -> bf16 (plain [n][k]) ----------------
__global__ void cvt_weights(const float* __restrict__ qw, const float* __restrict__ pw,
                            const float* __restrict__ f1, const float* __restrict__ f2,
                            unsigned short* __restrict__ o) {
  int i = blockIdx.x * 256 + threadIdx.x;
  if (i < 442368)        o[i] = f2bf(qw[i]);
  else if (i < 589824)   o[i] = f2bf(pw[i - 442368]);
  else if (i < 1179648)  o[i] = f2bf(f1[i - 589824]);
  else if (i < 1769472)  o[i] = f2bf(f2[i - 1179648]);
}

// ---------------- fused transpose + LN1: x[B,C,HW] -> xpb[N,C] bf16, xn[N,C] bf16 ---------
__global__ __launch_bounds__(256)
void tpose_ln(const float* __restrict__ x, unsigned short* __restrict__ xpb,
              unsigned short* __restrict__ xnb,
              const float* __restrict__ gam, const float* __restrict__ bet) {
  __shared__ float ft[64][385];
  __shared__ float mstat[64], rstat[64];
  const int tid = threadIdx.x;
  const int nb0 = blockIdx.x * 64;
  const int bb = nb0 / HW_, hw0 = nb0 - bb * HW_;
  const float* xb = x + (size_t)bb * C_ * HW_ + hw0;
#pragma unroll
  for (int p = 0; p < 24; ++p) {
    const int c = p * 16 + (tid >> 4);
    f32x4 v = *(const f32x4*)&xb[(size_t)c * HW_ + (tid & 15) * 4];
#pragma unroll
    for (int j = 0; j < 4; ++j) ft[(tid & 15) * 4 + j][c] = v[j];
  }
  __syncthreads();
  const int l16 = tid & 15, g16 = tid >> 4;
#pragma unroll
  for (int rr = 0; rr < 4; ++rr) {
    const int row = g16 * 4 + rr;
    float s = 0.f, ss = 0.f;
#pragma unroll
    for (int k2 = 0; k2 < 24; ++k2) { float v = ft[row][l16 + k2 * 16]; s += v; ss += v * v; }
    s += __shfl_xor(s, 8); ss += __shfl_xor(ss, 8);
    s += __shfl_xor(s, 4); ss += __shfl_xor(ss, 4);
    s += __shfl_xor(s, 2); ss += __shfl_xor(ss, 2);
    s += __shfl_xor(s, 1); ss += __shfl_xor(ss, 1);
    if (l16 == 0) {
      const float mean = s * (1.f / 384.f);
      const float var = ss * (1.f / 384.f) - mean * mean;
      mstat[row] = mean; rstat[row] = rsqrtf(var + 1e-5f);
    }
  }
  __syncthreads();
  const int row = tid >> 2, part = tid & 3;
  const float mean = mstat[row], rstd = rstat[row];
  unsigned short* xpr = xpb + (size_t)(nb0 + row) * C_ + part * 96;
  unsigned short* xr = xnb + (size_t)(nb0 + row) * C_ + part * 96;
#pragma unroll
  for (int q = 0; q < 12; ++q) {
    short8v oraw, oln;
#pragma unroll
    for (int e = 0; e < 8; ++e) {
      const int c = part * 96 + q * 8 + e;
      const float v = ft[row][c];
      oraw[e] = (short)f2bf(v);
      oln[e] = (short)f2bf((v - mean) * rstd * gam[c] + bet[c]);
    }
    *(short8v*)&xpr[q * 8] = oraw;
    *(short8v*)&xr[q * 8] = oln;
  }
}

// ---------------- row LayerNorm bf16 -> bf16 (LN2) ----------------
__global__ __launch_bounds__(256)
void ln_rows(const unsigned short* __restrict__ in, unsigned short* __restrict__ outb,
             const float* __restrict__ g, const float* __restrict__ bb) {
  const int row = blockIdx.x * 4 + (threadIdx.x >> 6);
  const int l = threadIdx.x & 63;
  float v[8]; float s = 0.f, ss = 0.f;
  if (l < 48) {
    short8v r = *(const short8v*)&in[(size_t)row * C_ + l * 8];
#pragma unroll
    for (int e = 0; e < 8; ++e) { v[e] = bf2f((unsigned short)r[e]); s += v[e]; ss += v[e] * v[e]; }
  }
#pragma unroll
  for (int off = 32; off; off >>= 1) { s += __shfl_xor(s, off); ss += __shfl_xor(ss, off); }
  const float mean = s * (1.f / 384.f);
  const float var = ss * (1.f / 384.f) - mean * mean;
  const float rstd = rsqrtf(var + 1e-5f);
  if (l < 48) {
    short8v o;
#pragma unroll
    for (int e = 0; e < 8; ++e) {
      const int c = l * 8 + e;
      o[e] = (short)f2bf((v[e] - mean) * rstd * g[c] + bb[c]);
    }
    *(short8v*)&outb[(size_t)row * C_ + l * 8] = o;
  }
}

// ---------------- GEMM: out[M,NOUT] = A[M,K] @ W[NOUT,K]^T ----------------
// MODE 0: bf16 out (qkv, no bias)        MODE 1: bf16 out = resid + v + bias (proj)
// MODE 2: bf16 out = gelu(v+bias) (fc1)  MODE 3: f32 d_out[B,C,HW] = resid+v+bias transposed
// All SWAP modes (0/1/2) now store via padded-LDS transpose -> coalesced 16B runs.
template <int MODE, int NOUT, int K>
__global__ __launch_bounds__(512, 4)
void gemmW(const unsigned short* __restrict__ A, const unsigned short* __restrict__ Wt,
           const float* __restrict__ bias, const unsigned short* __restrict__ resid,
           void* __restrict__ outp) {
  constexpr bool SWAP = (MODE != 3);
  constexpr int KT = K / 32;
  constexpr int SLOTU = 320 * 32;            // (128+192) rows x 32 cols ushorts = 20KB
  __shared__ unsigned short sm[4 * SLOTU];   // 80 KiB ring-4
  const int tid = threadIdx.x, l = tid & 63, wv = tid >> 6;
  const int wm = wv >> 2, wn = wv & 3;

  // bijective XCD swizzle (nwg % 8 == 0 for all grids), m-band contiguous per XCD
  const int nx = gridDim.x;
  const int nwg = nx * gridDim.y;
  const int bid = blockIdx.y * nx + blockIdx.x;
  const int wg = (bid & 7) * (nwg >> 3) + (bid >> 3);
  const int m0 = (wg / nx) * 128, n0 = (wg % nx) * 192;

  // staging: 20 chunks/stage (A: 0..7 = rows m0+16c.., B: 8..19 = rows n0+16(c-8)..)
  const int cpw = (wv >= 4) ? 2 : 3;         // chunks per wave (20 = 4*3 + 4*2)
  const int cg = (((l & 3) ^ ((l >> 3) & 3)) << 3);   // inverse-swizzled source col
  const unsigned short* gp[3]; int gd[3];
#pragma unroll
  for (int i = 0; i < 3; ++i) {
    const int ci = wv + 8 * i;               // i=2 only used when cpw==3
    const int rl = (ci < 20 ? ci : 0) * 16 + (l >> 2);
    gp[i] = (ci < 8) ? A + (size_t)(m0 + rl) * K + cg
                     : Wt + (size_t)(n0 + (rl - 128)) * K + cg;
    gd[i] = (ci < 20 ? ci : 0) * 512 + l * 8;
  }
  auto stage = [&](int t) {
    const int sb = (t & 3) * SLOTU;
    for (int i = 0; i < cpw; ++i) GLL(gp[i] + t * 32, &sm[sb + gd[i]]);
  };

  // fragment read offsets (swizzled): s = fr*4 + (g ^ ((fr>>1)&3))
  const int fr = l & 15, g = l >> 4, g4 = g * 4;
  const int sfr = (fr * 4 + (g ^ ((fr >> 1) & 3))) * 8;
  int aoff[4], boff[3];
#pragma unroll
  for (int mt = 0; mt < 4; ++mt) aoff[mt] = (wm * 4 + mt) * 512 + sfr;
#pragma unroll
  for (int nt = 0; nt < 3; ++nt) boff[nt] = (8 + wn * 3 + nt) * 512 + sfr;

  f32x4 acc[4][3] = {};

  stage(0); stage(1); stage(2);
  for (int t = 0; t < KT; ++t) {
    const int rem = KT - t;
    if (rem > 2) {
      if (cpw == 3) asm volatile("s_waitcnt vmcnt(6)" ::: "memory");
      else          asm volatile("s_waitcnt vmcnt(4)" ::: "memory");
    } else if (rem == 2) {
      if (cpw == 3) asm volatile("s_waitcnt vmcnt(3)" ::: "memory");
      else          asm volatile("s_waitcnt vmcnt(2)" ::: "memory");
    } else {
      asm volatile("s_waitcnt vmcnt(0)" ::: "memory");
    }
    __builtin_amdgcn_sched_barrier(0);
    __builtin_amdgcn_s_barrier();
    __builtin_amdgcn_sched_barrier(0);
    if (t + 3 < KT) stage(t + 3);
    __builtin_amdgcn_sched_barrier(0);
    const int sb = (t & 3) * SLOTU;
    short8v av[4], bv[3];
#pragma unroll
    for (int mt = 0; mt < 4; ++mt) av[mt] = *(const short8v*)&sm[sb + aoff[mt]];
#pragma unroll
    for (int nt = 0; nt < 3; ++nt) bv[nt] = *(const short8v*)&sm[sb + boff[nt]];
    __builtin_amdgcn_s_setprio(1);
#pragma unroll
    for (int mt = 0; mt < 4; ++mt)
#pragma unroll
      for (int nt = 0; nt < 3; ++nt)
        acc[mt][nt] = SWAP
          ? __builtin_amdgcn_mfma_f32_16x16x32_bf16(bv[nt], av[mt], acc[mt][nt], 0, 0, 0)
          : __builtin_amdgcn_mfma_f32_16x16x32_bf16(av[mt], bv[nt], acc[mt][nt], 0, 0, 0);
    __builtin_amdgcn_s_setprio(0);
    __builtin_amdgcn_sched_barrier(0);
  }

  if constexpr (SWAP) {
    // lane: m = wm*64 + mt*16 + fr ; n = wn*48 + nt*16 + g4 + j
    // dump raw acc (bf16) to padded LDS [128][200], then coalesced pass applies
    // bias/resid/gelu and stores 16B runs.
    __syncthreads();
#pragma unroll
    for (int mt = 0; mt < 4; ++mt) {
      const int ml = wm * 64 + mt * 16 + fr;
#pragma unroll
      for (int nt = 0; nt < 3; ++nt) {
        const int nl = wn * 48 + nt * 16 + g4;
        f32x4 v = acc[mt][nt];
        ushort4v pk;
#pragma unroll
        for (int j = 0; j < 4; ++j) pk[j] = f2bf(v[j]);
        *(ushort4v*)&sm[ml * 200 + nl] = pk;
      }
    }
    __syncthreads();
    unsigned short* op = (unsigned short*)outp;
#pragma unroll
    for (int it = 0; it < 6; ++it) {
      const int slot = it * 512 + tid;       // 128 rows x 24 groups
      const int row = slot / 24, grp = slot - row * 24;
      const int n = n0 + grp * 8;
      short8v v = *(const short8v*)&sm[row * 200 + grp * 8];
      if constexpr (MODE == 2) {
        const f32x4 b0 = *(const f32x4*)&bias[n];
        const f32x4 b1 = *(const f32x4*)&bias[n + 4];
#pragma unroll
        for (int e = 0; e < 8; ++e) {
          const float xv = bf2f((unsigned short)v[e]) + (e < 4 ? b0[e] : b1[e - 4]);
          v[e] = (short)f2bf(0.5f * xv * (1.f + erff(xv * 0.70710678118f)));
        }
      } else if constexpr (MODE == 1) {
        const f32x4 b0 = *(const f32x4*)&bias[n];
        const f32x4 b1 = *(const f32x4*)&bias[n + 4];
        const short8v r8 = *(const short8v*)&resid[(size_t)(m0 + row) * C_ + n];
#pragma unroll
        for (int e = 0; e < 8; ++e)
          v[e] = (short)f2bf(bf2f((unsigned short)v[e]) + (e < 4 ? b0[e] : b1[e - 4])
                             + bf2f((unsigned short)r8[e]));
      }
      *(short8v*)&op[(size_t)(m0 + row) * NOUT + n] = v;
    }
  } else {
    // MODE 3: lane: m = m0 + wm*64 + mt*16 + g4 + j ; c = n0 + wn*48 + nt*16 + fr
    __syncthreads();
    float* lf = (float*)sm;     // [96 c'][32 u] swizzled: idx = c'*128 + ((u^(c'&7))<<2)
    float* out = (float*)outp;
#pragma unroll
    for (int p = 0; p < 2; ++p) {
      if ((wn >> 1) == p) {
#pragma unroll
        for (int mt = 0; mt < 4; ++mt) {
          const int u = wm * 16 + mt * 4 + g;
#pragma unroll
          for (int nt = 0; nt < 3; ++nt) {
            const int cl = (wn & 1) * 48 + nt * 16 + fr;
            const int cgl = n0 + p * 96 + cl;
            const float bo = bias[cgl];
            f32x4 v = acc[mt][nt];
#pragma unroll
            for (int j = 0; j < 4; ++j)
              v[j] = v[j] + bo + bf2f(resid[(size_t)(m0 + u * 4 + j) * C_ + cgl]);
            *(f32x4*)&lf[cl * 128 + ((u ^ (cl & 7)) << 2)] = v;
          }
        }
      }
      __syncthreads();
#pragma unroll
      for (int i = 0; i < 6; ++i) {
        const int slot = tid + 512 * i;      // 96 cols x 32 row-chunks
        const int u = slot & 31, cl = slot >> 5;
        f32x4 v = *(const f32x4*)&lf[cl * 128 + ((u ^ (cl & 7)) << 2)];
        const int cgl = n0 + p * 96 + cl;
        const int mg = m0 + u * 4;
        const int bb = mg / HW_, hw = mg - bb * HW_;
        *(f32x4*)&out[((size_t)bb * C_ + cgl) * HW_ + hw] = v;
      }
      __syncthreads();
    }
  }
}

// ---------------- multi-dilate local attention (+xn) ----------------
__global__ __launch_bounds__(256)
void attn_kernel(const unsigned short* __restrict__ qkv,
                 const unsigned short* __restrict__ xn,
                 unsigned short* __restrict__ aout) {
  const int gid = blockIdx.x * 256 + threadIdx.x;
  const int n = gid / 12;
  const int r = gid - n * 12;
  const int dil = (r >> 2) + 1;
  const int b = n / HW_;
  const int hw = n - b * HW_;
  const int h = hw / W_;
  const int w = hw - h * W_;

  const size_t base = (size_t)n * C3_ + (size_t)r * 32;
  float q[32];
  {
    const short8v* vp = (const short8v*)(qkv + base);
#pragma unroll
    for (int c8 = 0; c8 < 4; ++c8) {
      short8v v = vp[c8];
#pragma unroll
      for (int e = 0; e < 8; ++e) q[c8 * 8 + e] = bf2f((unsigned short)v[e]);
    }
  }

  float logit[9];
#pragma unroll
  for (int ti = 0; ti < 3; ++ti)
#pragma unroll
    for (int tj = 0; tj < 3; ++tj) {
      const int t = ti * 3 + tj;
      const int hn = h + (ti - 1) * dil, wn = w + (tj - 1) * dil;
      if ((unsigned)hn < 56u && (unsigned)wn < 56u) {
        const int nb = n + (ti - 1) * dil * W_ + (tj - 1) * dil;
        const short8v* kp = (const short8v*)(qkv + (size_t)nb * C3_ + C_ + (size_t)r * 32);
        float dot = 0.f;
#pragma unroll
        for (int c8 = 0; c8 < 4; ++c8) {
          short8v v = kp[c8];
#pragma unroll
          for (int e = 0; e < 8; ++e) dot += q[c8 * 8 + e] * bf2f((unsigned short)v[e]);
        }
        logit[t] = dot * 0.17677669529663688f;
      } else {
        logit[t] = 0.f;  // zero-padded taps participate with logit 0
      }
    }

  float mx = logit[0];
#pragma unroll
  for (int t = 1; t < 9; ++t) mx = fmaxf(mx, logit[t]);
  float wgt[9]; float se = 0.f;
#pragma unroll
  for (int t = 0; t < 9; ++t) { wgt[t] = __expf(logit[t] - mx); se += wgt[t]; }
  const float inv = 1.f / se;

  float acc[32];
#pragma unroll
  for (int c = 0; c < 32; ++c) acc[c] = 0.f;
#pragma unroll
  for (int ti = 0; ti < 3; ++ti)
#pragma unroll
    for (int tj = 0; tj < 3; ++tj) {
      const int t = ti * 3 + tj;
      const int hn = h + (ti - 1) * dil, wn = w + (tj - 1) * dil;
      if ((unsigned)hn < 56u && (unsigned)wn < 56u) {
        const int nb = n + (ti - 1) * dil * W_ + (tj - 1) * dil;
        const short8v* vp = (const short8v*)(qkv + (size_t)nb * C3_ + 2 * C_ + (size_t)r * 32);
        const float wt = wgt[t];
#pragma unroll
        for (int c8 = 0; c8 < 4; ++c8) {
          short8v v = vp[c8];
#pragma unroll
          for (int e = 0; e < 8; ++e) acc[c8 * 8 + e] += wt * bf2f((unsigned short)v[e]);
        }
      }
    }

  const size_t obase = (size_t)n * C_ + (size_t)r * 32;
  const short8v* xv = (const short8v*)(xn + obase);
  short8v ov[4];
#pragma unroll
  for (int c8 = 0; c8 < 4; ++c8) {
    short8v v = xv[c8];
#pragma unroll
    for (int e = 0; e < 8; ++e)
      ov[c8][e] = (short)f2bf(acc[c8 * 8 + e] * inv + bf2f((unsigned short)v[e]));
  }
  short8v* op = (short8v*)(aout + obase);
#pragma unroll
  for (int c8 = 0; c8 < 4; ++c8) op[c8] = ov[c8];
}

extern "C" void kernel_launch(void* const* d_in, const int* in_sizes, int n_in,
                              void* d_out, int out_size, void* d_ws, size_t ws_size,
                              hipStream_t stream) {
  const float* x = (const float*)d_in[0];
  const float* qkv_w = (const float*)d_in[1];
  const float* proj_w = (const float*)d_in[2];
  const float* proj_b = (const float*)d_in[3];
  const float* n1_g = (const float*)d_in[4];
  const float* n1_b = (const float*)d_in[5];
  const float* n2_g = (const float*)d_in[6];
  const float* n2_b = (const float*)d_in[7];
  const float* fc1_w = (const float*)d_in[8];
  const float* fc1_b = (const float*)d_in[9];
  const float* fc2_w = (const float*)d_in[10];
  const float* fc2_b = (const float*)d_in[11];

  char* ws = (char*)d_ws;
  unsigned short* xpb = (unsigned short*)ws;                     // [N,C] bf16 (x transposed)
  unsigned short* xn = (unsigned short*)(ws + 19267584);         // [N,C] bf16 (LN1/LN2 out)
  unsigned short* qkvb = (unsigned short*)(ws + 38535168);       // [N,1152] bf16
  unsigned short* abuf = (unsigned short*)(ws + 96337920);       // [N,C] bf16
  unsigned short* y = (unsigned short*)(ws + 115605504);         // [N,C] bf16 residual stream
  unsigned short* hbuf = qkvb;                                   // [N,1536] bf16 (reuse)
  unsigned short* wq = (unsigned short*)(ws + 134873088);        // weights bf16 [n][k]
  unsigned short* wp = wq + 442368;
  unsigned short* wf1 = wp + 147456;
  unsigned short* wf2 = wf1 + 589824;

  cvt_weights<<<6912, 256, 0, stream>>>(qkv_w, proj_w, fc1_w, fc2_w, wq);
  tpose_ln<<<392, 256, 0, stream>>>(x, xpb, xn, n1_g, n1_b);
  gemmW<0, C3_, C_><<<dim3(6, 196), 512, 0, stream>>>(xn, wq, nullptr, nullptr, qkvb);
  attn_kernel<<<1176, 256, 0, stream>>>(qkvb, xn, abuf);
  gemmW<1, C_, C_><<<dim3(2, 196), 512, 0, stream>>>(abuf, wp, proj_b, xpb, y);
  ln_rows<<<6272, 256, 0, stream>>>(y, xn, n2_g, n2_b);
  gemmW<2, HID_, C_><<<dim3(8, 196), 512, 0, stream>>>(xn, wf1, fc1_b, nullptr, hbuf);
  gemmW<3, C_, HID_><<<dim3(2, 196), 512, 0, stream>>>(hbuf, wf2, fc2_b, y, d_out);
}